// Round 1
// baseline (646.894 us; speedup 1.0000x reference)
//
#include <hip/hip_runtime.h>
#include <hip/hip_bf16.h>

// Problem: B=8, T=4096, D=512, OUT=1. M = B*T = 32768.
// Pipeline: x->bf16; gates GEMM (fused f/i/h~ -> a,u); chunked scan; layer2; LN+proj.

#define MROWS 32768
#define DDIM  512
#define TLEN  4096
#define BSZ   8
#define NCHUNK 64
#define CLEN   64

typedef __attribute__((ext_vector_type(8))) __bf16 bf16x8;
typedef __attribute__((ext_vector_type(4))) float f32x4;
typedef __attribute__((ext_vector_type(4))) unsigned short ushort4_t;

static __device__ __forceinline__ unsigned short f2bf(float f) {
    unsigned int u = __float_as_uint(f);
    u = (u + 0x7FFFu + ((u >> 16) & 1u)) >> 16;   // round-to-nearest-even
    return (unsigned short)u;
}

// ---------------- fp32 -> bf16 conversion (4 elems/thread) ----------------
__global__ void f32_to_bf16_kernel(const float* __restrict__ src,
                                   unsigned short* __restrict__ dst, int n4) {
    int i = blockIdx.x * blockDim.x + threadIdx.x;
    if (i < n4) {
        float4 v = reinterpret_cast<const float4*>(src)[i];
        ushort4_t o;
        o.x = f2bf(v.x); o.y = f2bf(v.y); o.z = f2bf(v.z); o.w = f2bf(v.w);
        reinterpret_cast<ushort4_t*>(dst)[i] = o;
    }
}

// ---------------- fused gate GEMM: a,u = gates(X @ {Wf,Wi,Wh}^T + b) -------
// X: [M][512] bf16 row-major. W*: [512][512] bf16 row-major (out,in).
// Tile: 64(M) x 64(N) per block, 4 waves in 2x2, each wave 32x32 (2x2 frags).
__global__ __launch_bounds__(256) void gates_gemm(
    const unsigned short* __restrict__ X,
    const unsigned short* __restrict__ Wf,
    const unsigned short* __restrict__ Wi,
    const unsigned short* __restrict__ Wh,
    const float* __restrict__ bf, const float* __restrict__ bi,
    const float* __restrict__ bh,
    float* __restrict__ a_out, float* __restrict__ u_out)
{
    const int tid  = threadIdx.x;
    const int lane = tid & 63;
    const int wave = tid >> 6;
    const int wm = wave >> 1, wn = wave & 1;
    const int m0 = blockIdx.y * 64 + wm * 32;
    const int n0 = blockIdx.x * 64 + wn * 32;
    const int lr = lane & 15;   // row/col within 16x16 frag
    const int kg = lane >> 4;   // k-group (0..3), 8 contiguous k each

    f32x4 accF[2][2], accI[2][2], accH[2][2];
    const f32x4 zero = {0.f, 0.f, 0.f, 0.f};
#pragma unroll
    for (int mi = 0; mi < 2; ++mi)
#pragma unroll
        for (int ni = 0; ni < 2; ++ni) {
            accF[mi][ni] = zero; accI[mi][ni] = zero; accH[mi][ni] = zero;
        }

    for (int k0 = 0; k0 < 512; k0 += 32) {
        const int kb = k0 + kg * 8;
        bf16x8 af[2];
#pragma unroll
        for (int mi = 0; mi < 2; ++mi)
            af[mi] = *reinterpret_cast<const bf16x8*>(
                X + (size_t)(m0 + mi * 16 + lr) * 512 + kb);
        bf16x8 bFv[2], bIv[2], bHv[2];
#pragma unroll
        for (int ni = 0; ni < 2; ++ni) {
            size_t off = (size_t)(n0 + ni * 16 + lr) * 512 + kb;
            bFv[ni] = *reinterpret_cast<const bf16x8*>(Wf + off);
            bIv[ni] = *reinterpret_cast<const bf16x8*>(Wi + off);
            bHv[ni] = *reinterpret_cast<const bf16x8*>(Wh + off);
        }
#pragma unroll
        for (int mi = 0; mi < 2; ++mi)
#pragma unroll
            for (int ni = 0; ni < 2; ++ni) {
                accF[mi][ni] = __builtin_amdgcn_mfma_f32_16x16x32_bf16(af[mi], bFv[ni], accF[mi][ni], 0, 0, 0);
                accI[mi][ni] = __builtin_amdgcn_mfma_f32_16x16x32_bf16(af[mi], bIv[ni], accI[mi][ni], 0, 0, 0);
                accH[mi][ni] = __builtin_amdgcn_mfma_f32_16x16x32_bf16(af[mi], bHv[ni], accH[mi][ni], 0, 0, 0);
            }
    }

    // epilogue: C/D layout col = lane&15, row = (lane>>4)*4 + reg
#pragma unroll
    for (int ni = 0; ni < 2; ++ni) {
        const int n = n0 + ni * 16 + lr;
        const float bfv = bf[n], biv = bi[n], bhv = bh[n];
#pragma unroll
        for (int mi = 0; mi < 2; ++mi) {
#pragma unroll
            for (int r = 0; r < 4; ++r) {
                const int m = m0 + mi * 16 + kg * 4 + r;
                float zf = accF[mi][ni][r] + bfv;
                float zi = accI[mi][ni][r] + biv;
                float zh = accH[mi][ni][r] + bhv;
                float fv = 1.0f / (1.0f + __expf(-zf));
                float iv = 1.0f / (1.0f + __expf(-zi));
                float dn = fv + iv;
                size_t idx = (size_t)m * 512 + n;
                a_out[idx] = fv / dn;
                u_out[idx] = (iv / dn) * zh;
            }
        }
    }
}

// ---------------- chunked scan (h_t = a_t * h_{t-1} + u_t) -----------------
// gid layout: b(3b) | c(6b) | d(9b); chunk = 64 steps.
__global__ void scan_pass1(const float* __restrict__ a, const float* __restrict__ u,
                           float* __restrict__ Asum, float* __restrict__ Usum) {
    int gid = blockIdx.x * 256 + threadIdx.x;   // 0..262143
    int d = gid & 511;
    int c = (gid >> 9) & 63;
    int b = gid >> 15;
    size_t base = ((size_t)(b * TLEN + c * CLEN)) * 512 + d;
    float A = 1.0f, h = 0.0f;
#pragma unroll 4
    for (int l = 0; l < CLEN; ++l) {
        float av = a[base + (size_t)l * 512];
        float uv = u[base + (size_t)l * 512];
        A *= av;
        h = av * h + uv;
    }
    Asum[gid] = A; Usum[gid] = h;
}

__global__ void scan_pass2(const float* __restrict__ Asum, const float* __restrict__ Usum,
                           float* __restrict__ Hinit) {
    int gid = blockIdx.x * 256 + threadIdx.x;  // 0..4095
    int d = gid & 511;
    int b = gid >> 9;
    float h = 0.0f;
    for (int c = 0; c < NCHUNK; ++c) {
        size_t idx = ((size_t)(b * NCHUNK + c)) * 512 + d;
        Hinit[idx] = h;
        h = Asum[idx] * h + Usum[idx];
    }
}

// mode=1: write bf16 to hb; mode=0: write fp32 to hf (hf may alias a -> no restrict)
__global__ void scan_pass3(const float* a, const float* u,
                           const float* __restrict__ Hinit,
                           float* hf, unsigned short* hb, int mode) {
    int gid = blockIdx.x * 256 + threadIdx.x;
    int d = gid & 511;
    int c = (gid >> 9) & 63;
    int b = gid >> 15;
    size_t base = ((size_t)(b * TLEN + c * CLEN)) * 512 + d;
    float h = Hinit[gid];
    for (int l = 0; l < CLEN; ++l) {
        size_t idx = base + (size_t)l * 512;
        float av = a[idx];
        float uv = u[idx];
        h = av * h + uv;
        if (mode) hb[idx] = f2bf(h);
        else      hf[idx] = h;
    }
}

// ---------------- residual + LayerNorm + out projection --------------------
__global__ __launch_bounds__(256) void final_kernel(
    const float* __restrict__ x, const float* __restrict__ h1,
    const float* __restrict__ g, const float* __restrict__ bvec,
    const float* __restrict__ Wout, const float* __restrict__ bout,
    float* __restrict__ out)
{
    int row = blockIdx.x;          // 0..32767
    int tid = threadIdx.x;
    size_t base = (size_t)row * 512;
    float r[2];
#pragma unroll
    for (int j = 0; j < 2; ++j) {
        int d = tid + j * 256;
        float hv = h1[base + d];
        float xv = x[base + d];
        if (hv != hv) hv = xv;    // NaN fallback
        r[j] = xv + hv;
    }
    float s = r[0] + r[1];
    float q = r[0] * r[0] + r[1] * r[1];
#pragma unroll
    for (int m = 32; m >= 1; m >>= 1) {
        s += __shfl_xor(s, m);
        q += __shfl_xor(q, m);
    }
    __shared__ float ss[4], sq[4], sp[4];
    int w = tid >> 6, lane = tid & 63;
    if (lane == 0) { ss[w] = s; sq[w] = q; }
    __syncthreads();
    float tot = ss[0] + ss[1] + ss[2] + ss[3];
    float totq = sq[0] + sq[1] + sq[2] + sq[3];
    float mu = tot * (1.0f / 512.0f);
    float var = totq * (1.0f / 512.0f) - mu * mu;
    float rstd = rsqrtf(var + 1e-5f);
    float p = 0.0f;
#pragma unroll
    for (int j = 0; j < 2; ++j) {
        int d = tid + j * 256;
        float nv = (r[j] - mu) * rstd * g[d] + bvec[d];
        p += nv * Wout[d];
    }
#pragma unroll
    for (int m = 32; m >= 1; m >>= 1) p += __shfl_xor(p, m);
    if (lane == 0) sp[w] = p;
    __syncthreads();
    if (tid == 0) out[row] = sp[0] + sp[1] + sp[2] + sp[3] + bout[0];
}

extern "C" void kernel_launch(void* const* d_in, const int* in_sizes, int n_in,
                              void* d_out, int out_size, void* d_ws, size_t ws_size,
                              hipStream_t stream) {
    const float* x    = (const float*)d_in[0];
    const float* Wf0  = (const float*)d_in[1];  const float* bf0 = (const float*)d_in[2];
    const float* Wi0  = (const float*)d_in[3];  const float* bi0 = (const float*)d_in[4];
    const float* Wh0  = (const float*)d_in[5];  const float* bh0 = (const float*)d_in[6];
    const float* Wf1  = (const float*)d_in[7];  const float* bf1 = (const float*)d_in[8];
    const float* Wi1  = (const float*)d_in[9];  const float* bi1 = (const float*)d_in[10];
    const float* Wh1  = (const float*)d_in[11]; const float* bh1 = (const float*)d_in[12];
    const float* ln_g = (const float*)d_in[13]; const float* ln_b = (const float*)d_in[14];
    const float* W_out = (const float*)d_in[15]; const float* b_out = (const float*)d_in[16];

    char* ws = (char*)d_ws;
    unsigned short* Xb = (unsigned short*)ws;  ws += (size_t)MROWS * DDIM * 2;   // 32 MB
    unsigned short* Wb[6];
    for (int i = 0; i < 6; ++i) { Wb[i] = (unsigned short*)ws; ws += (size_t)DDIM * DDIM * 2; }
    float* abuf = (float*)ws;  ws += (size_t)MROWS * DDIM * 4;                   // 64 MB
    float* ubuf = (float*)ws;  ws += (size_t)MROWS * DDIM * 4;                   // 64 MB
    float* Asum = (float*)ws;  ws += (size_t)BSZ * NCHUNK * DDIM * 4;
    float* Usum = (float*)ws;  ws += (size_t)BSZ * NCHUNK * DDIM * 4;
    float* Hinit = (float*)ws; ws += (size_t)BSZ * NCHUNK * DDIM * 4;
    unsigned short* h0b = (unsigned short*)ws; ws += (size_t)MROWS * DDIM * 2;   // 32 MB

    // casts
    f32_to_bf16_kernel<<<16384, 256, 0, stream>>>(x, Xb, MROWS * DDIM / 4);
    f32_to_bf16_kernel<<<256, 256, 0, stream>>>(Wf0, Wb[0], DDIM * DDIM / 4);
    f32_to_bf16_kernel<<<256, 256, 0, stream>>>(Wi0, Wb[1], DDIM * DDIM / 4);
    f32_to_bf16_kernel<<<256, 256, 0, stream>>>(Wh0, Wb[2], DDIM * DDIM / 4);
    f32_to_bf16_kernel<<<256, 256, 0, stream>>>(Wf1, Wb[3], DDIM * DDIM / 4);
    f32_to_bf16_kernel<<<256, 256, 0, stream>>>(Wi1, Wb[4], DDIM * DDIM / 4);
    f32_to_bf16_kernel<<<256, 256, 0, stream>>>(Wh1, Wb[5], DDIM * DDIM / 4);

    dim3 ggrid(DDIM / 64, MROWS / 64);   // (8, 512)

    // ---- layer 0 ----
    gates_gemm<<<ggrid, 256, 0, stream>>>(Xb, Wb[0], Wb[1], Wb[2], bf0, bi0, bh0, abuf, ubuf);
    scan_pass1<<<1024, 256, 0, stream>>>(abuf, ubuf, Asum, Usum);
    scan_pass2<<<16, 256, 0, stream>>>(Asum, Usum, Hinit);
    scan_pass3<<<1024, 256, 0, stream>>>(abuf, ubuf, Hinit, nullptr, h0b, 1);

    // ---- layer 1 ----
    gates_gemm<<<ggrid, 256, 0, stream>>>(h0b, Wb[3], Wb[4], Wb[5], bf1, bi1, bh1, abuf, ubuf);
    scan_pass1<<<1024, 256, 0, stream>>>(abuf, ubuf, Asum, Usum);
    scan_pass2<<<16, 256, 0, stream>>>(Asum, Usum, Hinit);
    scan_pass3<<<1024, 256, 0, stream>>>(abuf, ubuf, Hinit, abuf, nullptr, 0); // h1 in-place in abuf

    // ---- residual + LN + projection ----
    final_kernel<<<MROWS, 256, 0, stream>>>(x, abuf, ln_g, ln_b, W_out, b_out, (float*)d_out);
}

// Round 2
// 491.503 us; speedup vs baseline: 1.3162x; 1.3162x over previous
//
#include <hip/hip_runtime.h>
#include <hip/hip_bf16.h>
#include <stdint.h>

// Problem: B=8, T=4096, D=512, OUT=1. M = B*T = 32768.
// Pipeline: x->bf16; gates GEMM (LDS-staged, fused f/i/h~ -> a,u); chunked scan; layer2; LN+proj.

#define MROWS 32768
#define DDIM  512
#define TLEN  4096
#define BSZ   8
#define NCHUNK 64
#define CLEN   64

typedef __attribute__((ext_vector_type(8))) __bf16 bf16x8;
typedef __attribute__((ext_vector_type(4))) float f32x4;
typedef __attribute__((ext_vector_type(4))) unsigned short ushort4_t;

static __device__ __forceinline__ unsigned short f2bf(float f) {
    unsigned int u = __float_as_uint(f);
    u = (u + 0x7FFFu + ((u >> 16) & 1u)) >> 16;   // round-to-nearest-even
    return (unsigned short)u;
}

static __device__ __forceinline__ void gload_lds16(const void* gptr, void* ldsp) {
    __builtin_amdgcn_global_load_lds(
        (const __attribute__((address_space(1))) uint32_t*)gptr,
        (__attribute__((address_space(3))) uint32_t*)ldsp,
        16, 0, 0);
}

// ---------------- fp32 -> bf16 conversion (4 elems/thread) ----------------
__global__ void f32_to_bf16_kernel(const float* __restrict__ src,
                                   unsigned short* __restrict__ dst, int n4) {
    int i = blockIdx.x * blockDim.x + threadIdx.x;
    if (i < n4) {
        float4 v = reinterpret_cast<const float4*>(src)[i];
        ushort4_t o;
        o.x = f2bf(v.x); o.y = f2bf(v.y); o.z = f2bf(v.z); o.w = f2bf(v.w);
        reinterpret_cast<ushort4_t*>(dst)[i] = o;
    }
}

// ---------------- fused gate GEMM: a,u = gates(X @ {Wf,Wi,Wh}^T + b) -------
// X: [M][512] bf16 row-major. W*: [512][512] bf16 row-major (out,in).
// Block tile: 128(M) x 64(N); 4 waves in 2x2, each wave 64x32 (4x2 frags x 3 gates).
// LDS staging via global_load_lds width=16, BK=32, 2-barrier K-loop.
__global__ __launch_bounds__(256) void gates_gemm(
    const unsigned short* __restrict__ X,
    const unsigned short* __restrict__ Wf,
    const unsigned short* __restrict__ Wi,
    const unsigned short* __restrict__ Wh,
    const float* __restrict__ bf_, const float* __restrict__ bi_,
    const float* __restrict__ bh_,
    float* __restrict__ a_out, float* __restrict__ u_out)
{
    __shared__ __align__(16) unsigned short Alds[128 * 32];     // 8 KB
    __shared__ __align__(16) unsigned short Blds[3][64 * 32];   // 12 KB

    const int tid  = threadIdx.x;
    const int lane = tid & 63;
    const int wave = tid >> 6;
    const int wm = wave >> 1, wn = wave & 1;   // wave tile: 64m x 32n
    const int lr = lane & 15;
    const int kg = lane >> 4;

    const int mblk = blockIdx.y * 128;
    const int nblk = blockIdx.x * 64;

    // staging: each thread loads 16B; row = tid>>2 (64 rows/round), kcol = (tid&3)*8
    const int srow = tid >> 2;
    const int scol = (tid & 3) * 8;

    f32x4 accF[4][2], accI[4][2], accH[4][2];
    const f32x4 zero = {0.f, 0.f, 0.f, 0.f};
#pragma unroll
    for (int mi = 0; mi < 4; ++mi)
#pragma unroll
        for (int ni = 0; ni < 2; ++ni) {
            accF[mi][ni] = zero; accI[mi][ni] = zero; accH[mi][ni] = zero;
        }

    for (int k0 = 0; k0 < 512; k0 += 32) {
        __syncthreads();   // previous compute done before overwrite
        // stage A tile: 128 rows x 32 k (two 64-row rounds)
        gload_lds16(X + (size_t)(mblk + srow) * 512 + k0 + scol,
                    Alds + wave * 512);
        gload_lds16(X + (size_t)(mblk + 64 + srow) * 512 + k0 + scol,
                    Alds + 2048 + wave * 512);
        // stage B tiles: 64 rows x 32 k each
        gload_lds16(Wf + (size_t)(nblk + srow) * 512 + k0 + scol,
                    Blds[0] + wave * 512);
        gload_lds16(Wi + (size_t)(nblk + srow) * 512 + k0 + scol,
                    Blds[1] + wave * 512);
        gload_lds16(Wh + (size_t)(nblk + srow) * 512 + k0 + scol,
                    Blds[2] + wave * 512);
        __syncthreads();   // vmcnt drain + barrier

        bf16x8 afr[4];
#pragma unroll
        for (int mi = 0; mi < 4; ++mi) {
            const int row = wm * 64 + mi * 16 + lr;
            afr[mi] = *reinterpret_cast<const bf16x8*>(Alds + row * 32 + kg * 8);
        }
        bf16x8 bfr[3][2];
#pragma unroll
        for (int g = 0; g < 3; ++g)
#pragma unroll
            for (int ni = 0; ni < 2; ++ni) {
                const int row = wn * 32 + ni * 16 + lr;
                bfr[g][ni] = *reinterpret_cast<const bf16x8*>(Blds[g] + row * 32 + kg * 8);
            }
#pragma unroll
        for (int mi = 0; mi < 4; ++mi)
#pragma unroll
            for (int ni = 0; ni < 2; ++ni) {
                accF[mi][ni] = __builtin_amdgcn_mfma_f32_16x16x32_bf16(afr[mi], bfr[0][ni], accF[mi][ni], 0, 0, 0);
                accI[mi][ni] = __builtin_amdgcn_mfma_f32_16x16x32_bf16(afr[mi], bfr[1][ni], accI[mi][ni], 0, 0, 0);
                accH[mi][ni] = __builtin_amdgcn_mfma_f32_16x16x32_bf16(afr[mi], bfr[2][ni], accH[mi][ni], 0, 0, 0);
            }
    }

    // epilogue: C/D layout col = lane&15 (n), row = (lane>>4)*4 + r (m)
#pragma unroll
    for (int ni = 0; ni < 2; ++ni) {
        const int n = nblk + wn * 32 + ni * 16 + lr;
        const float bfv = bf_[n], biv = bi_[n], bhv = bh_[n];
#pragma unroll
        for (int mi = 0; mi < 4; ++mi) {
#pragma unroll
            for (int r = 0; r < 4; ++r) {
                const int m = mblk + wm * 64 + mi * 16 + kg * 4 + r;
                float zf = accF[mi][ni][r] + bfv;
                float zi = accI[mi][ni][r] + biv;
                float zh = accH[mi][ni][r] + bhv;
                float fv = 1.0f / (1.0f + __expf(-zf));
                float iv = 1.0f / (1.0f + __expf(-zi));
                float dn = fv + iv;
                size_t idx = (size_t)m * 512 + n;
                a_out[idx] = fv / dn;
                u_out[idx] = (iv / dn) * zh;
            }
        }
    }
}

// ---------------- chunked scan (h_t = a_t * h_{t-1} + u_t), float4 ---------
// summary idx4 = (b*64 + c)*128 + d4
__global__ void scan_pass1(const float4* __restrict__ a, const float4* __restrict__ u,
                           float4* __restrict__ Asum, float4* __restrict__ Usum) {
    int gid = blockIdx.x * 256 + threadIdx.x;   // 0..65535
    int d4 = gid & 127;
    int c = (gid >> 7) & 63;
    int b = gid >> 13;
    size_t base = (size_t)(b * TLEN + c * CLEN) * 128 + d4;
    float4 A = {1.f, 1.f, 1.f, 1.f};
    float4 h = {0.f, 0.f, 0.f, 0.f};
    for (int l = 0; l < CLEN; ++l) {
        float4 av = a[base + (size_t)l * 128];
        float4 uv = u[base + (size_t)l * 128];
        A.x *= av.x; A.y *= av.y; A.z *= av.z; A.w *= av.w;
        h.x = av.x * h.x + uv.x; h.y = av.y * h.y + uv.y;
        h.z = av.z * h.z + uv.z; h.w = av.w * h.w + uv.w;
    }
    Asum[gid] = A; Usum[gid] = h;
}

__global__ void scan_pass2(const float4* __restrict__ Asum, const float4* __restrict__ Usum,
                           float4* __restrict__ Hinit) {
    int t = blockIdx.x * 256 + threadIdx.x;  // 0..1023
    int d4 = t & 127;
    int b = t >> 7;
    float4 h = {0.f, 0.f, 0.f, 0.f};
    for (int c = 0; c < NCHUNK; ++c) {
        size_t idx = (size_t)(b * NCHUNK + c) * 128 + d4;
        Hinit[idx] = h;
        float4 A = Asum[idx]; float4 U = Usum[idx];
        h.x = A.x * h.x + U.x; h.y = A.y * h.y + U.y;
        h.z = A.z * h.z + U.z; h.w = A.w * h.w + U.w;
    }
}

// MODE=1: write bf16 (ushort4) to hb; MODE=0: write fp32 to hf (hf aliases a)
template <int MODE>
__global__ void scan_pass3(const float4* a, const float4* u,
                           const float4* __restrict__ Hinit,
                           float4* hf, ushort4_t* hb) {
    int gid = blockIdx.x * 256 + threadIdx.x;   // 0..65535
    int d4 = gid & 127;
    int c = (gid >> 7) & 63;
    int b = gid >> 13;
    size_t base = (size_t)(b * TLEN + c * CLEN) * 128 + d4;
    float4 h = Hinit[gid];
    for (int l = 0; l < CLEN; ++l) {
        size_t idx = base + (size_t)l * 128;
        float4 av = a[idx];
        float4 uv = u[idx];
        h.x = av.x * h.x + uv.x; h.y = av.y * h.y + uv.y;
        h.z = av.z * h.z + uv.z; h.w = av.w * h.w + uv.w;
        if (MODE) {
            ushort4_t o;
            o.x = f2bf(h.x); o.y = f2bf(h.y); o.z = f2bf(h.z); o.w = f2bf(h.w);
            hb[idx] = o;
        } else {
            hf[idx] = h;
        }
    }
}

// ---------------- residual + LayerNorm + out projection --------------------
__global__ __launch_bounds__(256) void final_kernel(
    const float* __restrict__ x, const float* __restrict__ h1,
    const float* __restrict__ g, const float* __restrict__ bvec,
    const float* __restrict__ Wout, const float* __restrict__ bout,
    float* __restrict__ out)
{
    int row = blockIdx.x;          // 0..32767
    int tid = threadIdx.x;
    size_t base = (size_t)row * 512;
    float r[2];
#pragma unroll
    for (int j = 0; j < 2; ++j) {
        int d = tid + j * 256;
        float hv = h1[base + d];
        float xv = x[base + d];
        if (hv != hv) hv = xv;    // NaN fallback
        r[j] = xv + hv;
    }
    float s = r[0] + r[1];
    float q = r[0] * r[0] + r[1] * r[1];
#pragma unroll
    for (int m = 32; m >= 1; m >>= 1) {
        s += __shfl_xor(s, m);
        q += __shfl_xor(q, m);
    }
    __shared__ float ss[4], sq[4], sp[4];
    int w = tid >> 6, lane = tid & 63;
    if (lane == 0) { ss[w] = s; sq[w] = q; }
    __syncthreads();
    float tot = ss[0] + ss[1] + ss[2] + ss[3];
    float totq = sq[0] + sq[1] + sq[2] + sq[3];
    float mu = tot * (1.0f / 512.0f);
    float var = totq * (1.0f / 512.0f) - mu * mu;
    float rstd = rsqrtf(var + 1e-5f);
    float p = 0.0f;
#pragma unroll
    for (int j = 0; j < 2; ++j) {
        int d = tid + j * 256;
        float nv = (r[j] - mu) * rstd * g[d] + bvec[d];
        p += nv * Wout[d];
    }
#pragma unroll
    for (int m = 32; m >= 1; m >>= 1) p += __shfl_xor(p, m);
    if (lane == 0) sp[w] = p;
    __syncthreads();
    if (tid == 0) out[row] = sp[0] + sp[1] + sp[2] + sp[3] + bout[0];
}

extern "C" void kernel_launch(void* const* d_in, const int* in_sizes, int n_in,
                              void* d_out, int out_size, void* d_ws, size_t ws_size,
                              hipStream_t stream) {
    const float* x    = (const float*)d_in[0];
    const float* Wf0  = (const float*)d_in[1];  const float* bf0 = (const float*)d_in[2];
    const float* Wi0  = (const float*)d_in[3];  const float* bi0 = (const float*)d_in[4];
    const float* Wh0  = (const float*)d_in[5];  const float* bh0 = (const float*)d_in[6];
    const float* Wf1  = (const float*)d_in[7];  const float* bf1 = (const float*)d_in[8];
    const float* Wi1  = (const float*)d_in[9];  const float* bi1 = (const float*)d_in[10];
    const float* Wh1  = (const float*)d_in[11]; const float* bh1 = (const float*)d_in[12];
    const float* ln_g = (const float*)d_in[13]; const float* ln_b = (const float*)d_in[14];
    const float* W_out = (const float*)d_in[15]; const float* b_out = (const float*)d_in[16];

    char* ws = (char*)d_ws;
    unsigned short* Xb = (unsigned short*)ws;  ws += (size_t)MROWS * DDIM * 2;   // 32 MB
    unsigned short* Wb[6];
    for (int i = 0; i < 6; ++i) { Wb[i] = (unsigned short*)ws; ws += (size_t)DDIM * DDIM * 2; }
    float* abuf = (float*)ws;  ws += (size_t)MROWS * DDIM * 4;                   // 64 MB
    float* ubuf = (float*)ws;  ws += (size_t)MROWS * DDIM * 4;                   // 64 MB
    float* Asum = (float*)ws;  ws += (size_t)BSZ * NCHUNK * DDIM * 4;
    float* Usum = (float*)ws;  ws += (size_t)BSZ * NCHUNK * DDIM * 4;
    float* Hinit = (float*)ws; ws += (size_t)BSZ * NCHUNK * DDIM * 4;
    unsigned short* h0b = (unsigned short*)ws; ws += (size_t)MROWS * DDIM * 2;   // 32 MB

    // casts
    f32_to_bf16_kernel<<<16384, 256, 0, stream>>>(x, Xb, MROWS * DDIM / 4);
    f32_to_bf16_kernel<<<256, 256, 0, stream>>>(Wf0, Wb[0], DDIM * DDIM / 4);
    f32_to_bf16_kernel<<<256, 256, 0, stream>>>(Wi0, Wb[1], DDIM * DDIM / 4);
    f32_to_bf16_kernel<<<256, 256, 0, stream>>>(Wh0, Wb[2], DDIM * DDIM / 4);
    f32_to_bf16_kernel<<<256, 256, 0, stream>>>(Wf1, Wb[3], DDIM * DDIM / 4);
    f32_to_bf16_kernel<<<256, 256, 0, stream>>>(Wi1, Wb[4], DDIM * DDIM / 4);
    f32_to_bf16_kernel<<<256, 256, 0, stream>>>(Wh1, Wb[5], DDIM * DDIM / 4);

    dim3 ggrid(DDIM / 64, MROWS / 128);   // (8, 256)

    // ---- layer 0 ----
    gates_gemm<<<ggrid, 256, 0, stream>>>(Xb, Wb[0], Wb[1], Wb[2], bf0, bi0, bh0, abuf, ubuf);
    scan_pass1<<<256, 256, 0, stream>>>((const float4*)abuf, (const float4*)ubuf,
                                        (float4*)Asum, (float4*)Usum);
    scan_pass2<<<4, 256, 0, stream>>>((const float4*)Asum, (const float4*)Usum, (float4*)Hinit);
    scan_pass3<1><<<256, 256, 0, stream>>>((const float4*)abuf, (const float4*)ubuf,
                                           (const float4*)Hinit, nullptr, (ushort4_t*)h0b);

    // ---- layer 1 ----
    gates_gemm<<<ggrid, 256, 0, stream>>>(h0b, Wb[3], Wb[4], Wb[5], bf1, bi1, bh1, abuf, ubuf);
    scan_pass1<<<256, 256, 0, stream>>>((const float4*)abuf, (const float4*)ubuf,
                                        (float4*)Asum, (float4*)Usum);
    scan_pass2<<<4, 256, 0, stream>>>((const float4*)Asum, (const float4*)Usum, (float4*)Hinit);
    scan_pass3<0><<<256, 256, 0, stream>>>((const float4*)abuf, (const float4*)ubuf,
                                           (const float4*)Hinit, (float4*)abuf, nullptr); // h1 in-place

    // ---- residual + LN + projection ----
    final_kernel<<<MROWS, 256, 0, stream>>>(x, abuf, ln_g, ln_b, W_out, b_out, (float*)d_out);
}

// Round 3
// 287.262 us; speedup vs baseline: 2.2519x; 1.7110x over previous
//
#include <hip/hip_runtime.h>
#include <hip/hip_bf16.h>
#include <stdint.h>

// B=8, T=4096, D=512, OUT=1. M = B*T = 32768.
// x->bf16; fused gates GEMM (bf16 a,u out); bf16 chunked scan; layer2; LN+proj.

#define MROWS 32768
#define DDIM  512
#define TLEN  4096
#define BSZ   8
#define NCHUNK 64
#define CLEN   64

typedef __attribute__((ext_vector_type(8))) __bf16 bf16x8;
typedef __attribute__((ext_vector_type(4))) float f32x4;
typedef __attribute__((ext_vector_type(4))) unsigned short ushort4_t;
typedef __attribute__((ext_vector_type(8))) unsigned short ushort8_t;
typedef __attribute__((ext_vector_type(2))) unsigned short ushort2_t;

static __device__ __forceinline__ unsigned short f2bf(float f) {
    unsigned int u = __float_as_uint(f);
    u = (u + 0x7FFFu + ((u >> 16) & 1u)) >> 16;   // RNE
    return (unsigned short)u;
}
static __device__ __forceinline__ float bf2f(unsigned short s) {
    return __uint_as_float(((unsigned int)s) << 16);
}
static __device__ __forceinline__ void gload_lds16(const void* gptr, void* ldsp) {
    __builtin_amdgcn_global_load_lds(
        (const __attribute__((address_space(1))) uint32_t*)gptr,
        (__attribute__((address_space(3))) uint32_t*)ldsp,
        16, 0, 0);
}

// ---------------- fp32 -> bf16 (4 elems/thread) ----------------
__global__ void f32_to_bf16_kernel(const float* __restrict__ src,
                                   unsigned short* __restrict__ dst, int n4) {
    int i = blockIdx.x * blockDim.x + threadIdx.x;
    if (i < n4) {
        float4 v = reinterpret_cast<const float4*>(src)[i];
        ushort4_t o;
        o.x = f2bf(v.x); o.y = f2bf(v.y); o.z = f2bf(v.z); o.w = f2bf(v.w);
        reinterpret_cast<ushort4_t*>(dst)[i] = o;
    }
}

// ---------------- fused gate GEMM ----------------
// Block: 512 thr / 8 waves (4m x 2n), wave tile 32x32, BM=128, BN=64, BK=64.
// LDS per buffer: A[128 rows][128B] + 3x B[64][128B] = 40KB; double-buffered = 80KB.
// Swizzle: element (row, colB) at byte (row*128 + colB) ^ ((row&7)<<4); staged by
// pre-swizzling the per-lane GLOBAL source column (linear LDS dest for gload_lds).
__global__ __launch_bounds__(512) void gates_gemm(
    const unsigned short* __restrict__ X,
    const unsigned short* __restrict__ Wf,
    const unsigned short* __restrict__ Wi,
    const unsigned short* __restrict__ Wh,
    const float* __restrict__ bf_, const float* __restrict__ bi_,
    const float* __restrict__ bh_,
    unsigned short* __restrict__ a_out, unsigned short* __restrict__ u_out)
{
    __shared__ __align__(16) unsigned short lds[2 * 20480];   // 80 KB

    const int tid  = threadIdx.x;
    const int lane = tid & 63;
    const int wave = tid >> 6;
    const int wm = wave >> 1, wn = wave & 1;      // 4m x 2n waves of 32x32
    const int lr  = lane & 15;
    const int kgl = lane >> 4;

    const int mblk = blockIdx.y * 128;
    const int nblk = blockIdx.x * 64;

    // staging source (pre-swizzled global column)
    const int srow = tid >> 3;                          // 0..63
    const int scol = ((tid & 7) ^ (srow & 7)) << 3;     // bf16 units
    const unsigned short* pA = X  + (size_t)(mblk + srow) * 512 + scol;
    const unsigned short* pF = Wf + (size_t)(nblk + srow) * 512 + scol;
    const unsigned short* pI = Wi + (size_t)(nblk + srow) * 512 + scol;
    const unsigned short* pH = Wh + (size_t)(nblk + srow) * 512 + scol;

    // LDS read offsets (ushort units), ks toggles via ^32
    int aoff[2], boff[2];
#pragma unroll
    for (int mi = 0; mi < 2; ++mi) {
        int row = wm * 32 + mi * 16 + lr;
        aoff[mi] = row * 64 + ((kgl ^ (row & 7)) << 3);
    }
#pragma unroll
    for (int ni = 0; ni < 2; ++ni) {
        int row = wn * 32 + ni * 16 + lr;
        boff[ni] = row * 64 + ((kgl ^ (row & 7)) << 3);
    }

    f32x4 accF[2][2], accI[2][2], accH[2][2];
    const f32x4 zero = {0.f, 0.f, 0.f, 0.f};
#pragma unroll
    for (int mi = 0; mi < 2; ++mi)
#pragma unroll
        for (int ni = 0; ni < 2; ++ni) {
            accF[mi][ni] = zero; accI[mi][ni] = zero; accH[mi][ni] = zero;
        }

#define STAGE(buf) do { \
    gload_lds16(pA,             (buf) + wave * 512);            \
    gload_lds16(pA + 64 * 512,  (buf) + 4096  + wave * 512);    \
    gload_lds16(pF,             (buf) + 8192  + wave * 512);    \
    gload_lds16(pI,             (buf) + 12288 + wave * 512);    \
    gload_lds16(pH,             (buf) + 16384 + wave * 512);    \
    pA += 64; pF += 64; pI += 64; pH += 64; } while (0)

    STAGE(lds);   // tile 0 -> buf0

    for (int t = 0; t < 8; ++t) {
        unsigned short* cbuf = lds + (t & 1) * 20480;
        unsigned short* nbuf = lds + ((t & 1) ^ 1) * 20480;
        if (t < 7) {
            STAGE(nbuf);
            asm volatile("s_waitcnt vmcnt(5)" ::: "memory");
        } else {
            asm volatile("s_waitcnt vmcnt(0)" ::: "memory");
        }
        __builtin_amdgcn_s_barrier();
        __builtin_amdgcn_sched_barrier(0);

#pragma unroll
        for (int ks = 0; ks < 2; ++ks) {
            const int kx = ks << 5;
            bf16x8 af[2];
#pragma unroll
            for (int mi = 0; mi < 2; ++mi)
                af[mi] = *reinterpret_cast<const bf16x8*>(cbuf + (aoff[mi] ^ kx));
            bf16x8 bF[2], bI[2], bH[2];
#pragma unroll
            for (int ni = 0; ni < 2; ++ni) {
                bF[ni] = *reinterpret_cast<const bf16x8*>(cbuf + 8192  + (boff[ni] ^ kx));
                bI[ni] = *reinterpret_cast<const bf16x8*>(cbuf + 12288 + (boff[ni] ^ kx));
                bH[ni] = *reinterpret_cast<const bf16x8*>(cbuf + 16384 + (boff[ni] ^ kx));
            }
#pragma unroll
            for (int mi = 0; mi < 2; ++mi)
#pragma unroll
                for (int ni = 0; ni < 2; ++ni) {
                    accF[mi][ni] = __builtin_amdgcn_mfma_f32_16x16x32_bf16(af[mi], bF[ni], accF[mi][ni], 0, 0, 0);
                    accI[mi][ni] = __builtin_amdgcn_mfma_f32_16x16x32_bf16(af[mi], bI[ni], accI[mi][ni], 0, 0, 0);
                    accH[mi][ni] = __builtin_amdgcn_mfma_f32_16x16x32_bf16(af[mi], bH[ni], accH[mi][ni], 0, 0, 0);
                }
        }
        __builtin_amdgcn_sched_barrier(0);
        __builtin_amdgcn_s_barrier();
        __builtin_amdgcn_sched_barrier(0);
    }
#undef STAGE

    // epilogue: col = lane&15 (n), row = kgl*4 + r (m)
#pragma unroll
    for (int ni = 0; ni < 2; ++ni) {
        const int n = nblk + wn * 32 + ni * 16 + lr;
        const float bfv = bf_[n], biv = bi_[n], bhv = bh_[n];
#pragma unroll
        for (int mi = 0; mi < 2; ++mi) {
#pragma unroll
            for (int r = 0; r < 4; ++r) {
                const int m = mblk + wm * 32 + mi * 16 + kgl * 4 + r;
                float zf = accF[mi][ni][r] + bfv;
                float zi = accI[mi][ni][r] + biv;
                float zh = accH[mi][ni][r] + bhv;
                float fv = 1.0f / (1.0f + __expf(-zf));
                float iv = 1.0f / (1.0f + __expf(-zi));
                float dn = fv + iv;
                size_t idx = (size_t)m * 512 + n;
                a_out[idx] = f2bf(fv / dn);
                u_out[idx] = f2bf((iv / dn) * zh);
            }
        }
    }
}

// ---------------- chunked scan on bf16 a,u ----------------
// thread: 8 d-cols; gid: d8(6b) | c(6b) | b(3b); row stride = 64 ushort8.
__global__ void scan_pass1(const ushort8_t* __restrict__ a, const ushort8_t* __restrict__ u,
                           float4* __restrict__ Asum, float4* __restrict__ Usum) {
    int gid = blockIdx.x * 256 + threadIdx.x;    // 0..32767
    int d8 = gid & 63;
    int c  = (gid >> 6) & 63;
    int b  = gid >> 12;
    size_t base = (size_t)(b * TLEN + c * CLEN) * 64 + d8;
    float A[8], h[8];
#pragma unroll
    for (int j = 0; j < 8; ++j) { A[j] = 1.f; h[j] = 0.f; }
#pragma unroll 2
    for (int l = 0; l < CLEN; ++l) {
        ushort8_t av8 = a[base + (size_t)l * 64];
        ushort8_t uv8 = u[base + (size_t)l * 64];
#pragma unroll
        for (int j = 0; j < 8; ++j) {
            float av = bf2f(av8[j]), uv = bf2f(uv8[j]);
            A[j] *= av;
            h[j] = av * h[j] + uv;
        }
    }
    size_t s4 = (size_t)(b * NCHUNK + c) * 128 + d8 * 2;
    Asum[s4]     = make_float4(A[0], A[1], A[2], A[3]);
    Asum[s4 + 1] = make_float4(A[4], A[5], A[6], A[7]);
    Usum[s4]     = make_float4(h[0], h[1], h[2], h[3]);
    Usum[s4 + 1] = make_float4(h[4], h[5], h[6], h[7]);
}

__global__ void scan_pass2(const float4* __restrict__ Asum, const float4* __restrict__ Usum,
                           float4* __restrict__ Hinit) {
    int t = blockIdx.x * 256 + threadIdx.x;  // 0..1023
    int d4 = t & 127;
    int b = t >> 7;
    float4 h = {0.f, 0.f, 0.f, 0.f};
    for (int c = 0; c < NCHUNK; ++c) {
        size_t idx = (size_t)(b * NCHUNK + c) * 128 + d4;
        Hinit[idx] = h;
        float4 A = Asum[idx]; float4 U = Usum[idx];
        h.x = A.x * h.x + U.x; h.y = A.y * h.y + U.y;
        h.z = A.z * h.z + U.z; h.w = A.w * h.w + U.w;
    }
}

__global__ void scan_pass3(const ushort8_t* __restrict__ a, const ushort8_t* __restrict__ u,
                           const float4* __restrict__ Hinit,
                           ushort8_t* __restrict__ hout) {
    int gid = blockIdx.x * 256 + threadIdx.x;
    int d8 = gid & 63;
    int c  = (gid >> 6) & 63;
    int b  = gid >> 12;
    size_t base = (size_t)(b * TLEN + c * CLEN) * 64 + d8;
    size_t s4 = (size_t)(b * NCHUNK + c) * 128 + d8 * 2;
    float4 h0 = Hinit[s4], h1 = Hinit[s4 + 1];
    float h[8] = {h0.x, h0.y, h0.z, h0.w, h1.x, h1.y, h1.z, h1.w};
#pragma unroll 2
    for (int l = 0; l < CLEN; ++l) {
        size_t idx = base + (size_t)l * 64;
        ushort8_t av8 = a[idx];
        ushort8_t uv8 = u[idx];
        ushort8_t o;
#pragma unroll
        for (int j = 0; j < 8; ++j) {
            float av = bf2f(av8[j]), uv = bf2f(uv8[j]);
            h[j] = av * h[j] + uv;
            o[j] = f2bf(h[j]);
        }
        hout[idx] = o;
    }
}

// ---------------- residual + LayerNorm + out projection ----------------
__global__ __launch_bounds__(256) void final_kernel(
    const float* __restrict__ x, const unsigned short* __restrict__ h1,
    const float* __restrict__ g, const float* __restrict__ bvec,
    const float* __restrict__ Wout, const float* __restrict__ bout,
    float* __restrict__ out)
{
    int row = blockIdx.x;          // 0..32767
    int tid = threadIdx.x;
    size_t base = (size_t)row * 512;
    ushort2_t hv2 = *reinterpret_cast<const ushort2_t*>(h1 + base + tid * 2);
    float2 xv2 = *reinterpret_cast<const float2*>(x + base + tid * 2);
    float r[2];
#pragma unroll
    for (int j = 0; j < 2; ++j) {
        float hv = bf2f(hv2[j]);
        float xv = (j == 0) ? xv2.x : xv2.y;
        if (hv != hv) hv = xv;    // NaN fallback
        r[j] = xv + hv;
    }
    float s = r[0] + r[1];
    float q = r[0] * r[0] + r[1] * r[1];
#pragma unroll
    for (int m = 32; m >= 1; m >>= 1) {
        s += __shfl_xor(s, m);
        q += __shfl_xor(q, m);
    }
    __shared__ float ss[4], sq[4], sp[4];
    int w = tid >> 6, lane = tid & 63;
    if (lane == 0) { ss[w] = s; sq[w] = q; }
    __syncthreads();
    float tot  = ss[0] + ss[1] + ss[2] + ss[3];
    float totq = sq[0] + sq[1] + sq[2] + sq[3];
    float mu = tot * (1.0f / 512.0f);
    float var = totq * (1.0f / 512.0f) - mu * mu;
    float rstd = rsqrtf(var + 1e-5f);
    float p = 0.0f;
#pragma unroll
    for (int j = 0; j < 2; ++j) {
        int d = tid * 2 + j;
        float nv = (r[j] - mu) * rstd * g[d] + bvec[d];
        p += nv * Wout[d];
    }
#pragma unroll
    for (int m = 32; m >= 1; m >>= 1) p += __shfl_xor(p, m);
    if (lane == 0) sp[w] = p;
    __syncthreads();
    if (tid == 0) out[row] = sp[0] + sp[1] + sp[2] + sp[3] + bout[0];
}

extern "C" void kernel_launch(void* const* d_in, const int* in_sizes, int n_in,
                              void* d_out, int out_size, void* d_ws, size_t ws_size,
                              hipStream_t stream) {
    const float* x    = (const float*)d_in[0];
    const float* Wf0  = (const float*)d_in[1];  const float* bf0 = (const float*)d_in[2];
    const float* Wi0  = (const float*)d_in[3];  const float* bi0 = (const float*)d_in[4];
    const float* Wh0  = (const float*)d_in[5];  const float* bh0 = (const float*)d_in[6];
    const float* Wf1  = (const float*)d_in[7];  const float* bf1 = (const float*)d_in[8];
    const float* Wi1  = (const float*)d_in[9];  const float* bi1 = (const float*)d_in[10];
    const float* Wh1  = (const float*)d_in[11]; const float* bh1 = (const float*)d_in[12];
    const float* ln_g = (const float*)d_in[13]; const float* ln_b = (const float*)d_in[14];
    const float* W_out = (const float*)d_in[15]; const float* b_out = (const float*)d_in[16];

    char* ws = (char*)d_ws;
    unsigned short* Xb = (unsigned short*)ws;  ws += (size_t)MROWS * DDIM * 2;   // 32 MB
    unsigned short* Wb[6];
    for (int i = 0; i < 6; ++i) { Wb[i] = (unsigned short*)ws; ws += (size_t)DDIM * DDIM * 2; }
    unsigned short* abuf = (unsigned short*)ws; ws += (size_t)MROWS * DDIM * 2;  // 32 MB
    unsigned short* ubuf = (unsigned short*)ws; ws += (size_t)MROWS * DDIM * 2;  // 32 MB
    float* Asum = (float*)ws;  ws += (size_t)BSZ * NCHUNK * DDIM * 4;
    float* Usum = (float*)ws;  ws += (size_t)BSZ * NCHUNK * DDIM * 4;
    float* Hinit = (float*)ws; ws += (size_t)BSZ * NCHUNK * DDIM * 4;
    unsigned short* h0b = (unsigned short*)ws; ws += (size_t)MROWS * DDIM * 2;   // 32 MB
    unsigned short* h1b = (unsigned short*)ws; ws += (size_t)MROWS * DDIM * 2;   // 32 MB

    // casts
    f32_to_bf16_kernel<<<16384, 256, 0, stream>>>(x, Xb, MROWS * DDIM / 4);
    f32_to_bf16_kernel<<<256, 256, 0, stream>>>(Wf0, Wb[0], DDIM * DDIM / 4);
    f32_to_bf16_kernel<<<256, 256, 0, stream>>>(Wi0, Wb[1], DDIM * DDIM / 4);
    f32_to_bf16_kernel<<<256, 256, 0, stream>>>(Wh0, Wb[2], DDIM * DDIM / 4);
    f32_to_bf16_kernel<<<256, 256, 0, stream>>>(Wf1, Wb[3], DDIM * DDIM / 4);
    f32_to_bf16_kernel<<<256, 256, 0, stream>>>(Wi1, Wb[4], DDIM * DDIM / 4);
    f32_to_bf16_kernel<<<256, 256, 0, stream>>>(Wh1, Wb[5], DDIM * DDIM / 4);

    dim3 ggrid(DDIM / 64, MROWS / 128);   // (8, 256)

    // ---- layer 0 ----
    gates_gemm<<<ggrid, 512, 0, stream>>>(Xb, Wb[0], Wb[1], Wb[2], bf0, bi0, bh0, abuf, ubuf);
    scan_pass1<<<128, 256, 0, stream>>>((const ushort8_t*)abuf, (const ushort8_t*)ubuf,
                                        (float4*)Asum, (float4*)Usum);
    scan_pass2<<<4, 256, 0, stream>>>((const float4*)Asum, (const float4*)Usum, (float4*)Hinit);
    scan_pass3<<<128, 256, 0, stream>>>((const ushort8_t*)abuf, (const ushort8_t*)ubuf,
                                        (const float4*)Hinit, (ushort8_t*)h0b);

    // ---- layer 1 ----
    gates_gemm<<<ggrid, 512, 0, stream>>>(h0b, Wb[3], Wb[4], Wb[5], bf1, bi1, bh1, abuf, ubuf);
    scan_pass1<<<128, 256, 0, stream>>>((const ushort8_t*)abuf, (const ushort8_t*)ubuf,
                                        (float4*)Asum, (float4*)Usum);
    scan_pass2<<<4, 256, 0, stream>>>((const float4*)Asum, (const float4*)Usum, (float4*)Hinit);
    scan_pass3<<<128, 256, 0, stream>>>((const ushort8_t*)abuf, (const ushort8_t*)ubuf,
                                        (const float4*)Hinit, (ushort8_t*)h1b);

    // ---- residual + LN + projection ----
    final_kernel<<<MROWS, 256, 0, stream>>>(x, h1b, ln_g, ln_b, W_out, b_out, (float*)d_out);
}

// Round 4
// 250.126 us; speedup vs baseline: 2.5863x; 1.1485x over previous
//
#include <hip/hip_runtime.h>
#include <hip/hip_bf16.h>
#include <stdint.h>

// B=8, T=4096, D=512, OUT=1. M = B*T = 32768.
// cast; fused gates GEMM (XCD-swizzled, bf16 a,u); bf16 chunked scan; layer2; LN+proj.

#define MROWS 32768
#define DDIM  512
#define TLEN  4096
#define BSZ   8
#define NCHUNK 64
#define CLEN   64

typedef __attribute__((ext_vector_type(8))) __bf16 bf16x8;
typedef __attribute__((ext_vector_type(4))) float f32x4;
typedef __attribute__((ext_vector_type(4))) unsigned short ushort4_t;
typedef __attribute__((ext_vector_type(2))) unsigned short ushort2_t;

static __device__ __forceinline__ unsigned short f2bf(float f) {
    unsigned int u = __float_as_uint(f);
    u = (u + 0x7FFFu + ((u >> 16) & 1u)) >> 16;   // RNE
    return (unsigned short)u;
}
static __device__ __forceinline__ float bf2f(unsigned short s) {
    return __uint_as_float(((unsigned int)s) << 16);
}
static __device__ __forceinline__ void gload_lds16(const void* gptr, void* ldsp) {
    __builtin_amdgcn_global_load_lds(
        (const __attribute__((address_space(1))) uint32_t*)gptr,
        (__attribute__((address_space(3))) uint32_t*)ldsp,
        16, 0, 0);
}

// ---------------- merged fp32 -> bf16 cast (x + 6 W) ----------------
// x: 4194304 float4s; each W: 65536 float4s; Wb buffers are contiguous.
__global__ __launch_bounds__(256) void cast_all(
    const float4* __restrict__ x,
    const float4* __restrict__ w0, const float4* __restrict__ w1,
    const float4* __restrict__ w2, const float4* __restrict__ w3,
    const float4* __restrict__ w4, const float4* __restrict__ w5,
    ushort4_t* __restrict__ xb, ushort4_t* __restrict__ wb)
{
    int i = blockIdx.x * 256 + threadIdx.x;    // 0 .. 4587519
    float4 v;
    ushort4_t* dst;
    if (i < 4194304) {
        v = x[i];
        dst = xb + i;
    } else {
        int j = i - 4194304;
        int wsel = j >> 16;
        int rem = j & 65535;
        const float4* src = (wsel == 0) ? w0 : (wsel == 1) ? w1 : (wsel == 2) ? w2
                          : (wsel == 3) ? w3 : (wsel == 4) ? w4 : w5;
        v = src[rem];
        dst = wb + j;
    }
    ushort4_t o;
    o.x = f2bf(v.x); o.y = f2bf(v.y); o.z = f2bf(v.z); o.w = f2bf(v.w);
    *dst = o;
}

// ---------------- fused gate GEMM ----------------
// 256 thr / 4 waves (2m x 2n), wave tile 64x32, BM=128, BN=64, BK=64.
// LDS/buf: A[128][128B] 16KB + 3x B[64][128B] 24KB = 40KB; dbuf 80KB (2 blocks/CU).
// Swizzle: byte (row*128 + colB) ^ ((row&7)<<4); staged via pre-swizzled global col.
// XCD swizzle: all 8 n-blocks of an A-row-tile run on the same XCD.
__global__ __launch_bounds__(256) void gates_gemm(
    const unsigned short* __restrict__ X,
    const unsigned short* __restrict__ Wf,
    const unsigned short* __restrict__ Wi,
    const unsigned short* __restrict__ Wh,
    const float* __restrict__ bf_, const float* __restrict__ bi_,
    const float* __restrict__ bh_,
    unsigned short* __restrict__ a_out, unsigned short* __restrict__ u_out)
{
    __shared__ __align__(16) unsigned short lds[2 * 20480];   // 80 KB

    const int tid  = threadIdx.x;
    const int lane = tid & 63;
    const int wave = tid >> 6;                 // 0..3
    const int wm = wave >> 1, wn = wave & 1;   // 2m x 2n waves of 64x32
    const int lr  = lane & 15;
    const int kgl = lane >> 4;

    // XCD-aware bijective swizzle: 2048 blocks, xcd = id&7 gets by in [xcd*32, xcd*32+32),
    // with the 8 bx-blocks of each by temporally adjacent on that XCD.
    const int w = blockIdx.x;
    const int xcd = w & 7;
    const int s = w >> 3;                      // 0..255
    const int by = xcd * 32 + (s >> 3);        // 0..255
    const int bx = s & 7;                      // 0..7
    const int mblk = by * 128;
    const int nblk = bx * 64;

    // staging source (pre-swizzled global column); 10 gload_lds per thread per tile
    const int srow = tid >> 3;                          // 0..31
    const int scol = ((tid & 7) ^ (srow & 7)) << 3;     // bf16 units
    const unsigned short* pA = X  + (size_t)(mblk + srow) * 512 + scol;
    const unsigned short* pF = Wf + (size_t)(nblk + srow) * 512 + scol;
    const unsigned short* pI = Wi + (size_t)(nblk + srow) * 512 + scol;
    const unsigned short* pH = Wh + (size_t)(nblk + srow) * 512 + scol;

    // LDS read offsets (ushort units); ks toggles via ^32
    int aoff[4], boff[2];
#pragma unroll
    for (int mi = 0; mi < 4; ++mi) {
        int row = wm * 64 + mi * 16 + lr;
        aoff[mi] = row * 64 + ((kgl ^ (row & 7)) << 3);
    }
#pragma unroll
    for (int ni = 0; ni < 2; ++ni) {
        int row = wn * 32 + ni * 16 + lr;
        boff[ni] = row * 64 + ((kgl ^ (row & 7)) << 3);
    }

    f32x4 accF[4][2], accI[4][2], accH[4][2];
    const f32x4 zero = {0.f, 0.f, 0.f, 0.f};
#pragma unroll
    for (int mi = 0; mi < 4; ++mi)
#pragma unroll
        for (int ni = 0; ni < 2; ++ni) {
            accF[mi][ni] = zero; accI[mi][ni] = zero; accH[mi][ni] = zero;
        }

#define STAGE(buf) do { \
    gload_lds16(pA,            (buf) + wave * 512);             \
    gload_lds16(pA + 32 * 512, (buf) + 2048  + wave * 512);     \
    gload_lds16(pA + 64 * 512, (buf) + 4096  + wave * 512);     \
    gload_lds16(pA + 96 * 512, (buf) + 6144  + wave * 512);     \
    gload_lds16(pF,            (buf) + 8192  + wave * 512);     \
    gload_lds16(pF + 32 * 512, (buf) + 10240 + wave * 512);     \
    gload_lds16(pI,            (buf) + 12288 + wave * 512);     \
    gload_lds16(pI + 32 * 512, (buf) + 14336 + wave * 512);     \
    gload_lds16(pH,            (buf) + 16384 + wave * 512);     \
    gload_lds16(pH + 32 * 512, (buf) + 18432 + wave * 512);     \
    pA += 64; pF += 64; pI += 64; pH += 64; } while (0)

    STAGE(lds);   // tile 0 -> buf0

    for (int t = 0; t < 8; ++t) {
        unsigned short* cbuf = lds + (t & 1) * 20480;
        unsigned short* nbuf = lds + ((t & 1) ^ 1) * 20480;
        if (t < 7) {
            STAGE(nbuf);
            asm volatile("s_waitcnt vmcnt(10)" ::: "memory");
        } else {
            asm volatile("s_waitcnt vmcnt(0)" ::: "memory");
        }
        __builtin_amdgcn_s_barrier();
        __builtin_amdgcn_sched_barrier(0);

#pragma unroll
        for (int ks = 0; ks < 2; ++ks) {
            const int kx = ks << 5;
            bf16x8 af[4];
#pragma unroll
            for (int mi = 0; mi < 4; ++mi)
                af[mi] = *reinterpret_cast<const bf16x8*>(cbuf + (aoff[mi] ^ kx));
            bf16x8 bF[2], bI[2], bH[2];
#pragma unroll
            for (int ni = 0; ni < 2; ++ni) {
                bF[ni] = *reinterpret_cast<const bf16x8*>(cbuf + 8192  + (boff[ni] ^ kx));
                bI[ni] = *reinterpret_cast<const bf16x8*>(cbuf + 12288 + (boff[ni] ^ kx));
                bH[ni] = *reinterpret_cast<const bf16x8*>(cbuf + 16384 + (boff[ni] ^ kx));
            }
            __builtin_amdgcn_s_setprio(1);
#pragma unroll
            for (int mi = 0; mi < 4; ++mi)
#pragma unroll
                for (int ni = 0; ni < 2; ++ni) {
                    accF[mi][ni] = __builtin_amdgcn_mfma_f32_16x16x32_bf16(af[mi], bF[ni], accF[mi][ni], 0, 0, 0);
                    accI[mi][ni] = __builtin_amdgcn_mfma_f32_16x16x32_bf16(af[mi], bI[ni], accI[mi][ni], 0, 0, 0);
                    accH[mi][ni] = __builtin_amdgcn_mfma_f32_16x16x32_bf16(af[mi], bH[ni], accH[mi][ni], 0, 0, 0);
                }
            __builtin_amdgcn_s_setprio(0);
        }
        __builtin_amdgcn_sched_barrier(0);
        __builtin_amdgcn_s_barrier();
        __builtin_amdgcn_sched_barrier(0);
    }
#undef STAGE

    // epilogue: col = lane&15 (n), row = kgl*4 + r (m)
#pragma unroll
    for (int ni = 0; ni < 2; ++ni) {
        const int n = nblk + wn * 32 + ni * 16 + lr;
        const float bfv = bf_[n], biv = bi_[n], bhv = bh_[n];
#pragma unroll
        for (int mi = 0; mi < 4; ++mi) {
#pragma unroll
            for (int r = 0; r < 4; ++r) {
                const int m = mblk + wm * 64 + mi * 16 + kgl * 4 + r;
                float zf = accF[mi][ni][r] + bfv;
                float zi = accI[mi][ni][r] + biv;
                float zh = accH[mi][ni][r] + bhv;
                float fv = 1.0f / (1.0f + __expf(-zf));
                float iv = 1.0f / (1.0f + __expf(-zi));
                float dn = fv + iv;
                size_t idx = (size_t)m * 512 + n;
                a_out[idx] = f2bf(fv / dn);
                u_out[idx] = f2bf((iv / dn) * zh);
            }
        }
    }
}

// ---------------- chunked scan on bf16 a,u (float4-granularity d) ----------
// gid: d4(7b) | c(6b) | b(3b) -> 65536 threads; row stride = 128 ushort4.
__global__ void scan_pass1(const ushort4_t* __restrict__ a, const ushort4_t* __restrict__ u,
                           float4* __restrict__ Asum, float4* __restrict__ Usum) {
    int gid = blockIdx.x * 256 + threadIdx.x;    // 0..65535
    int d4 = gid & 127;
    int c  = (gid >> 7) & 63;
    int b  = gid >> 13;
    size_t base = (size_t)(b * TLEN + c * CLEN) * 128 + d4;
    float A[4] = {1.f, 1.f, 1.f, 1.f};
    float h[4] = {0.f, 0.f, 0.f, 0.f};
#pragma unroll 4
    for (int l = 0; l < CLEN; ++l) {
        ushort4_t av4 = a[base + (size_t)l * 128];
        ushort4_t uv4 = u[base + (size_t)l * 128];
#pragma unroll
        for (int j = 0; j < 4; ++j) {
            float av = bf2f(av4[j]), uv = bf2f(uv4[j]);
            A[j] *= av;
            h[j] = av * h[j] + uv;
        }
    }
    size_t s4 = (size_t)(b * NCHUNK + c) * 128 + d4;
    Asum[s4] = make_float4(A[0], A[1], A[2], A[3]);
    Usum[s4] = make_float4(h[0], h[1], h[2], h[3]);
}

__global__ void scan_pass2(const float4* __restrict__ Asum, const float4* __restrict__ Usum,
                           float4* __restrict__ Hinit) {
    int t = blockIdx.x * 256 + threadIdx.x;  // 0..1023
    int d4 = t & 127;
    int b = t >> 7;
    float4 h = {0.f, 0.f, 0.f, 0.f};
    for (int c = 0; c < NCHUNK; ++c) {
        size_t idx = (size_t)(b * NCHUNK + c) * 128 + d4;
        Hinit[idx] = h;
        float4 A = Asum[idx]; float4 U = Usum[idx];
        h.x = A.x * h.x + U.x; h.y = A.y * h.y + U.y;
        h.z = A.z * h.z + U.z; h.w = A.w * h.w + U.w;
    }
}

__global__ void scan_pass3(const ushort4_t* __restrict__ a, const ushort4_t* __restrict__ u,
                           const float4* __restrict__ Hinit,
                           ushort4_t* __restrict__ hout) {
    int gid = blockIdx.x * 256 + threadIdx.x;   // 0..65535
    int d4 = gid & 127;
    int c  = (gid >> 7) & 63;
    int b  = gid >> 13;
    size_t base = (size_t)(b * TLEN + c * CLEN) * 128 + d4;
    size_t s4 = (size_t)(b * NCHUNK + c) * 128 + d4;
    float4 h0 = Hinit[s4];
    float h[4] = {h0.x, h0.y, h0.z, h0.w};
#pragma unroll 4
    for (int l = 0; l < CLEN; ++l) {
        size_t idx = base + (size_t)l * 128;
        ushort4_t av4 = a[idx];
        ushort4_t uv4 = u[idx];
        ushort4_t o;
#pragma unroll
        for (int j = 0; j < 4; ++j) {
            float av = bf2f(av4[j]), uv = bf2f(uv4[j]);
            h[j] = av * h[j] + uv;
            o[j] = f2bf(h[j]);
        }
        hout[idx] = o;
    }
}

// ---------------- residual + LayerNorm + out projection ----------------
__global__ __launch_bounds__(256) void final_kernel(
    const float* __restrict__ x, const unsigned short* __restrict__ h1,
    const float* __restrict__ g, const float* __restrict__ bvec,
    const float* __restrict__ Wout, const float* __restrict__ bout,
    float* __restrict__ out)
{
    int row = blockIdx.x;          // 0..32767
    int tid = threadIdx.x;
    size_t base = (size_t)row * 512;
    ushort2_t hv2 = *reinterpret_cast<const ushort2_t*>(h1 + base + tid * 2);
    float2 xv2 = *reinterpret_cast<const float2*>(x + base + tid * 2);
    float r[2];
#pragma unroll
    for (int j = 0; j < 2; ++j) {
        float hv = bf2f(hv2[j]);
        float xv = (j == 0) ? xv2.x : xv2.y;
        if (hv != hv) hv = xv;    // NaN fallback
        r[j] = xv + hv;
    }
    float s = r[0] + r[1];
    float q = r[0] * r[0] + r[1] * r[1];
#pragma unroll
    for (int m = 32; m >= 1; m >>= 1) {
        s += __shfl_xor(s, m);
        q += __shfl_xor(q, m);
    }
    __shared__ float ss[4], sq[4], sp[4];
    int w = tid >> 6, lane = tid & 63;
    if (lane == 0) { ss[w] = s; sq[w] = q; }
    __syncthreads();
    float tot  = ss[0] + ss[1] + ss[2] + ss[3];
    float totq = sq[0] + sq[1] + sq[2] + sq[3];
    float mu = tot * (1.0f / 512.0f);
    float var = totq * (1.0f / 512.0f) - mu * mu;
    float rstd = rsqrtf(var + 1e-5f);
    float p = 0.0f;
#pragma unroll
    for (int j = 0; j < 2; ++j) {
        int d = tid * 2 + j;
        float nv = (r[j] - mu) * rstd * g[d] + bvec[d];
        p += nv * Wout[d];
    }
#pragma unroll
    for (int m = 32; m >= 1; m >>= 1) p += __shfl_xor(p, m);
    if (lane == 0) sp[w] = p;
    __syncthreads();
    if (tid == 0) out[row] = sp[0] + sp[1] + sp[2] + sp[3] + bout[0];
}

extern "C" void kernel_launch(void* const* d_in, const int* in_sizes, int n_in,
                              void* d_out, int out_size, void* d_ws, size_t ws_size,
                              hipStream_t stream) {
    const float* x    = (const float*)d_in[0];
    const float* Wf0  = (const float*)d_in[1];  const float* bf0 = (const float*)d_in[2];
    const float* Wi0  = (const float*)d_in[3];  const float* bi0 = (const float*)d_in[4];
    const float* Wh0  = (const float*)d_in[5];  const float* bh0 = (const float*)d_in[6];
    const float* Wf1  = (const float*)d_in[7];  const float* bf1 = (const float*)d_in[8];
    const float* Wi1  = (const float*)d_in[9];  const float* bi1 = (const float*)d_in[10];
    const float* Wh1  = (const float*)d_in[11]; const float* bh1 = (const float*)d_in[12];
    const float* ln_g = (const float*)d_in[13]; const float* ln_b = (const float*)d_in[14];
    const float* W_out = (const float*)d_in[15]; const float* b_out = (const float*)d_in[16];

    char* ws = (char*)d_ws;
    unsigned short* Xb = (unsigned short*)ws;  ws += (size_t)MROWS * DDIM * 2;   // 32 MB
    unsigned short* Wball = (unsigned short*)ws;                                 // 6 contiguous W
    unsigned short* Wb[6];
    for (int i = 0; i < 6; ++i) { Wb[i] = (unsigned short*)ws; ws += (size_t)DDIM * DDIM * 2; }
    unsigned short* abuf = (unsigned short*)ws; ws += (size_t)MROWS * DDIM * 2;  // 32 MB
    unsigned short* ubuf = (unsigned short*)ws; ws += (size_t)MROWS * DDIM * 2;  // 32 MB
    float* Asum = (float*)ws;  ws += (size_t)BSZ * NCHUNK * DDIM * 4;
    float* Usum = (float*)ws;  ws += (size_t)BSZ * NCHUNK * DDIM * 4;
    float* Hinit = (float*)ws; ws += (size_t)BSZ * NCHUNK * DDIM * 4;
    unsigned short* h0b = (unsigned short*)ws; ws += (size_t)MROWS * DDIM * 2;   // 32 MB
    unsigned short* h1b = (unsigned short*)ws; ws += (size_t)MROWS * DDIM * 2;   // 32 MB

    // merged casts: 4194304 (x) + 6*65536 (W) float4s = 4587520 -> 17920 blocks
    cast_all<<<17920, 256, 0, stream>>>(
        (const float4*)x, (const float4*)Wf0, (const float4*)Wi0, (const float4*)Wh0,
        (const float4*)Wf1, (const float4*)Wi1, (const float4*)Wh1,
        (ushort4_t*)Xb, (ushort4_t*)Wball);

    // ---- layer 0 ----
    gates_gemm<<<2048, 256, 0, stream>>>(Xb, Wb[0], Wb[1], Wb[2], bf0, bi0, bh0, abuf, ubuf);
    scan_pass1<<<256, 256, 0, stream>>>((const ushort4_t*)abuf, (const ushort4_t*)ubuf,
                                        (float4*)Asum, (float4*)Usum);
    scan_pass2<<<4, 256, 0, stream>>>((const float4*)Asum, (const float4*)Usum, (float4*)Hinit);
    scan_pass3<<<256, 256, 0, stream>>>((const ushort4_t*)abuf, (const ushort4_t*)ubuf,
                                        (const float4*)Hinit, (ushort4_t*)h0b);

    // ---- layer 1 ----
    gates_gemm<<<2048, 256, 0, stream>>>(h0b, Wb[3], Wb[4], Wb[5], bf1, bi1, bh1, abuf, ubuf);
    scan_pass1<<<256, 256, 0, stream>>>((const ushort4_t*)abuf, (const ushort4_t*)ubuf,
                                        (float4*)Asum, (float4*)Usum);
    scan_pass2<<<4, 256, 0, stream>>>((const float4*)Asum, (const float4*)Usum, (float4*)Hinit);
    scan_pass3<<<256, 256, 0, stream>>>((const ushort4_t*)abuf, (const ushort4_t*)ubuf,
                                        (const float4*)Hinit, (ushort4_t*)h1b);

    // ---- residual + LN + projection ----
    final_kernel<<<MROWS, 256, 0, stream>>>(x, h1b, ln_g, ln_b, W_out, b_out, (float*)d_out);
}